// Round 1
// baseline (309.507 us; speedup 1.0000x reference)
//
#include <hip/hip_runtime.h>
#include <hip/hip_bf16.h>

#define B_SZ 1024
#define T_LEN 8192
#define NBINS 819            // T//10
#define PSD_W (2*NBINS)      // 1638
#define PSD_LDA 1664         // padded stride (16B-aligned rows)
#define PI_F 3.14159265358979323846f

// ---------------------------------------------------------------------------
// Kernel 1: normalize feature rows (B x 256)
// ---------------------------------------------------------------------------
__global__ __launch_bounds__(256) void normalize_kernel(
    const float* __restrict__ f, float* __restrict__ fn) {
  int i = blockIdx.x;
  int t = threadIdx.x;
  float v = f[(size_t)i * 256 + t];
  float s = v * v;
  #pragma unroll
  for (int o = 32; o; o >>= 1) s += __shfl_down(s, o);
  __shared__ float buf[4];
  if ((t & 63) == 0) buf[t >> 6] = s;
  __syncthreads();
  float norm = sqrtf(buf[0] + buf[1] + buf[2] + buf[3]);
  norm = fmaxf(norm, 1e-12f);
  fn[(size_t)i * 256 + t] = v / norm;
}

// ---------------------------------------------------------------------------
// Kernel 2: per-trajectory stats. One block per trajectory.
//  - loads the 8192x4 rows once (float4)
//  - packed complex FFT of (v0*w) + i*(v1*w), radix-2 DIF in LDS
//  - writes psd bins 0..818 for both channels (stride PSD_LDA)
//  - v_mean and winding
// ---------------------------------------------------------------------------
__global__ __launch_bounds__(256) void traj_stats_kernel(
    const float4* __restrict__ traj,
    float* __restrict__ psd,
    float2* __restrict__ vmean,
    float2* __restrict__ wind) {
  __shared__ float2 z[T_LEN];   // 64 KB

  const int b = blockIdx.x;
  const int tid = threadIdx.x;
  const float4* row = traj + (size_t)b * T_LEN;

  float sum0 = 0.f, sum1 = 0.f;
  float ph0x = 0.f, ph0z = 0.f, ph1x = 0.f, ph1z = 0.f;
  const float wstep = 2.0f * PI_F / (float)T_LEN;

  for (int t = tid; t < T_LEN; t += 256) {
    float4 r = row[t];
    sum0 += r.y;
    sum1 += r.w;
    if (t == 0)        { ph0x = r.x; ph0z = r.z; }
    if (t == T_LEN-1)  { ph1x = r.x; ph1z = r.z; }
    float w = 0.5f * (1.0f - __cosf(wstep * (float)t));
    z[t] = make_float2(r.y * w, r.w * w);
  }
  __syncthreads();

  // radix-2 DIF, 13 stages; output bit-reversed
  int ls = 12;
  for (int span = T_LEN >> 1; span >= 1; span >>= 1, --ls) {
    const float ang_scale = -PI_F / (float)span;  // exact pow2 division
    for (int t = tid; t < (T_LEN >> 1); t += 256) {
      int j  = t & (span - 1);
      int i0 = ((t >> ls) << (ls + 1)) | j;
      int i1 = i0 + span;
      float2 a = z[i0];
      float2 c = z[i1];
      float2 u = make_float2(a.x + c.x, a.y + c.y);
      float2 d = make_float2(a.x - c.x, a.y - c.y);
      float sn, cs;
      __sincosf(ang_scale * (float)j, &sn, &cs);
      z[i0] = u;
      z[i1] = make_float2(d.x * cs - d.y * sn, d.x * sn + d.y * cs);
    }
    __syncthreads();
  }

  // unpack the two real-signal spectra; psd = |F|^2, bins 0..818
  for (int k = tid; k < NBINS; k += 256) {
    int r1 = (int)(__brev((unsigned)k) >> 19);
    int r2 = (k == 0) ? 0 : (int)(__brev((unsigned)(T_LEN - k)) >> 19);
    float2 Zk = z[r1];
    float2 Zn = z[r2];
    float fxr = 0.5f * (Zk.x + Zn.x);
    float fxi = 0.5f * (Zk.y - Zn.y);
    float fyr = 0.5f * (Zk.y + Zn.y);
    float fyi = 0.5f * (Zn.x - Zk.x);
    psd[(size_t)b * PSD_LDA + 2*k]     = fxr*fxr + fxi*fxi;
    psd[(size_t)b * PSD_LDA + 2*k + 1] = fyr*fyr + fyi*fyi;
  }
  __syncthreads();

  // reductions reusing LDS
  float* zf = (float*)z;
  zf[tid]       = sum0;
  zf[256 + tid] = sum1;
  if (tid == 255) { zf[512] = ph1x; zf[513] = ph1z; }
  __syncthreads();
  if (tid == 0) {
    float s0 = 0.f, s1 = 0.f;
    for (int q = 0; q < 256; ++q) { s0 += zf[q]; s1 += zf[256 + q]; }
    vmean[b] = make_float2(s0 / (float)T_LEN, s1 / (float)T_LEN);
    const float inv2pi = 0.15915494309189535f;
    wind[b] = make_float2(fabsf(rintf((zf[512] - ph0x) * inv2pi)),
                          fabsf(rintf((zf[513] - ph0z) * inv2pi)));
  }
}

// ---------------------------------------------------------------------------
// Kernel 3: C = A * A^T for A (N x K, row stride lda), fp32 tiled 64x64
// ---------------------------------------------------------------------------
__global__ __launch_bounds__(256) void aat_kernel(
    const float* __restrict__ A, float* __restrict__ C,
    int N, int K, int lda) {
  __shared__ float As[64][33];
  __shared__ float Bs[64][33];
  const int tid = threadIdx.x;
  const int i0 = blockIdx.y * 64;
  const int j0 = blockIdx.x * 64;
  const int tx = tid & 15, ty = tid >> 4;

  float acc[4][4] = {};

  for (int k0 = 0; k0 < K; k0 += 32) {
    // 64x32 tile: linear index e = pass*256 + tid; row = e>>5, kk = e&31
    #pragma unroll
    for (int pass = 0; pass < 8; ++pass) {
      int e = pass * 256 + tid;
      int r = e >> 5;
      int kk = e & 31;
      int kg = k0 + kk;
      float va = (kg < K) ? A[(size_t)(i0 + r) * lda + kg] : 0.0f;
      float vb = (kg < K) ? A[(size_t)(j0 + r) * lda + kg] : 0.0f;
      As[r][kk] = va;
      Bs[r][kk] = vb;
    }
    __syncthreads();
    #pragma unroll
    for (int kk = 0; kk < 32; ++kk) {
      float a0 = As[ty*4+0][kk], a1 = As[ty*4+1][kk];
      float a2 = As[ty*4+2][kk], a3 = As[ty*4+3][kk];
      float b0 = Bs[tx*4+0][kk], b1 = Bs[tx*4+1][kk];
      float b2 = Bs[tx*4+2][kk], b3 = Bs[tx*4+3][kk];
      acc[0][0] += a0*b0; acc[0][1] += a0*b1; acc[0][2] += a0*b2; acc[0][3] += a0*b3;
      acc[1][0] += a1*b0; acc[1][1] += a1*b1; acc[1][2] += a1*b2; acc[1][3] += a1*b3;
      acc[2][0] += a2*b0; acc[2][1] += a2*b1; acc[2][2] += a2*b2; acc[2][3] += a2*b3;
      acc[3][0] += a3*b0; acc[3][1] += a3*b1; acc[3][2] += a3*b2; acc[3][3] += a3*b3;
    }
    __syncthreads();
  }
  #pragma unroll
  for (int r = 0; r < 4; ++r)
    #pragma unroll
    for (int c = 0; c < 4; ++c)
      C[(size_t)(i0 + ty*4 + r) * N + (j0 + tx*4 + c)] = acc[r][c];
}

// ---------------------------------------------------------------------------
// Kernel 4: per-row loss. One block per row i.
// ---------------------------------------------------------------------------
__global__ __launch_bounds__(256) void loss_rows_kernel(
    const float* __restrict__ S,     // f fn^T raw dot (B x B)
    const float* __restrict__ G,     // psd gram (B x B); diag = n2
    const float* __restrict__ labels,    // B x 3
    const float* __restrict__ scales,    // 1
    const float2* __restrict__ vmean,
    const float2* __restrict__ wind,
    float* __restrict__ row_loss) {
  const int i = blockIdx.x;
  const int tid = threadIdx.x;
  const float inv_scale = 1.0f / scales[0];
  const float l0 = labels[i*3+0], l1 = labels[i*3+1], l2 = labels[i*3+2];
  const float2 vmi = vmean[i];
  const float2 wi  = wind[i];
  const float n2i  = G[(size_t)i * B_SZ + i];
  const float normi = sqrtf(n2i);

  float posw = 0.f, den = 0.f;
  for (int j = tid; j < B_SZ; j += 256) {
    if (j == i) continue;
    float e = __expf(S[(size_t)i * B_SZ + j] * 10.0f);  // /TEMPERATURE
    den += e;

    float d0 = (labels[j*3+0] - l0) * inv_scale;
    float d1 = (labels[j*3+1] - l1) * inv_scale;
    float d2v = (labels[j*3+2] - l2) * inv_scale;
    float pd = sqrtf(d0*d0 + d1*d1 + d2v*d2v);
    float pw = __expf(-pd * 10.0f);

    float2 vmj = vmean[j];
    float dvx = vmi.x - vmj.x, dvy = vmi.y - vmj.y;
    float v_sim = __expf(-sqrtf(dvx*dvx + dvy*dvy) * 2.0f);  // /0.5

    float n2j = G[(size_t)j * B_SZ + j];
    float g   = G[(size_t)i * B_SZ + j];
    float dd  = fmaxf(n2i + n2j - 2.0f * g, 0.0f);
    float psd_dist = sqrtf(dd);
    // triu+transpose: norm from the smaller index
    float norma = (i < j) ? normi : sqrtf(n2j);
    float psd_sim = __expf(-psd_dist / (norma + 1e-8f));

    float2 wj = wind[j];
    float w_sim = (wi.x == wj.x && wi.y == wj.y) ? 1.0f : 0.0f;

    float kin = 0.4f * v_sim + 0.4f * psd_sim + 0.2f * w_sim;
    posw += e * pw * kin;
  }

  #pragma unroll
  for (int o = 32; o; o >>= 1) {
    posw += __shfl_down(posw, o);
    den  += __shfl_down(den, o);
  }
  __shared__ float bp[4], bd[4];
  if ((tid & 63) == 0) { bp[tid >> 6] = posw; bd[tid >> 6] = den; }
  __syncthreads();
  if (tid == 0) {
    float P = bp[0] + bp[1] + bp[2] + bp[3];
    float D = bd[0] + bd[1] + bd[2] + bd[3];
    row_loss[i] = -logf((P + 1e-8f) / (D + 1e-8f));
  }
}

// ---------------------------------------------------------------------------
// Kernel 5: mean of row losses -> scalar
// ---------------------------------------------------------------------------
__global__ __launch_bounds__(256) void reduce_mean_kernel(
    const float* __restrict__ row_loss, float* __restrict__ out) {
  int tid = threadIdx.x;
  float s = 0.f;
  for (int i = tid; i < B_SZ; i += 256) s += row_loss[i];
  #pragma unroll
  for (int o = 32; o; o >>= 1) s += __shfl_down(s, o);
  __shared__ float buf[4];
  if ((tid & 63) == 0) buf[tid >> 6] = s;
  __syncthreads();
  if (tid == 0) out[0] = (buf[0] + buf[1] + buf[2] + buf[3]) / (float)B_SZ;
}

// ---------------------------------------------------------------------------
extern "C" void kernel_launch(void* const* d_in, const int* in_sizes, int n_in,
                              void* d_out, int out_size, void* d_ws, size_t ws_size,
                              hipStream_t stream) {
  const float* features = (const float*)d_in[0];   // 1024 x 256
  const float* labels   = (const float*)d_in[1];   // 1024 x 3
  const float* traj     = (const float*)d_in[2];   // 1024 x 8192 x 4
  const float* scales   = (const float*)d_in[3];   // 1

  float* ws = (float*)d_ws;
  float* f_n  = ws;                                    // 262144
  float* psd  = f_n + (size_t)B_SZ * 256;              // 1024*1664
  float* G    = psd + (size_t)B_SZ * PSD_LDA;          // 1024*1024
  float* S    = G + (size_t)B_SZ * B_SZ;               // 1024*1024
  float2* vmean = (float2*)(S + (size_t)B_SZ * B_SZ);  // 1024 float2
  float2* wind  = vmean + B_SZ;                        // 1024 float2
  float* row_loss = (float*)(wind + B_SZ);             // 1024

  normalize_kernel<<<B_SZ, 256, 0, stream>>>(features, f_n);
  traj_stats_kernel<<<B_SZ, 256, 0, stream>>>((const float4*)traj, psd, vmean, wind);

  dim3 grid16(16, 16);
  aat_kernel<<<grid16, 256, 0, stream>>>(psd, G, B_SZ, PSD_W, PSD_LDA);
  aat_kernel<<<grid16, 256, 0, stream>>>(f_n, S, B_SZ, 256, 256);

  loss_rows_kernel<<<B_SZ, 256, 0, stream>>>(S, G, labels, scales, vmean, wind, row_loss);
  reduce_mean_kernel<<<1, 256, 0, stream>>>(row_loss, (float*)d_out);
}

// Round 2
// 117.091 us; speedup vs baseline: 2.6433x; 2.6433x over previous
//
#include <hip/hip_runtime.h>
#include <hip/hip_bf16.h>

#define B_SZ 1024
#define T_LEN 8192
#define NBINS 819            // T//10
#define PSD_LDA 1664         // padded bf16 row stride (zero-padded 1638..1663)
#define PI_F 3.14159265358979323846f

typedef __attribute__((ext_vector_type(8))) short bf16x8;
typedef __attribute__((ext_vector_type(4))) float f32x4;

// ---------------------------------------------------------------------------
// Kernel 1: normalize feature rows (B x 256) -> bf16
// ---------------------------------------------------------------------------
__global__ __launch_bounds__(256) void normalize_kernel(
    const float* __restrict__ f, __hip_bfloat16* __restrict__ fn) {
  int i = blockIdx.x;
  int t = threadIdx.x;
  float v = f[(size_t)i * 256 + t];
  float s = v * v;
  #pragma unroll
  for (int o = 32; o; o >>= 1) s += __shfl_down(s, o);
  __shared__ float buf[4];
  if ((t & 63) == 0) buf[t >> 6] = s;
  __syncthreads();
  float norm = sqrtf(buf[0] + buf[1] + buf[2] + buf[3]);
  norm = fmaxf(norm, 1e-12f);
  fn[(size_t)i * 256 + t] = __float2bfloat16(v / norm);
}

// ---------------------------------------------------------------------------
// Kernel 2: per-trajectory stats. One block per trajectory.
//  packed complex FFT of (v0*w) + i*(v1*w), radix-2 DIF in 64KB LDS;
//  psd written as bf16 (stride PSD_LDA, zero padded); v_mean; winding.
// ---------------------------------------------------------------------------
__global__ __launch_bounds__(256) void traj_stats_kernel(
    const float4* __restrict__ traj,
    __hip_bfloat16* __restrict__ psd,
    float2* __restrict__ vmean,
    float2* __restrict__ wind) {
  __shared__ float2 z[T_LEN];   // 64 KB

  const int b = blockIdx.x;
  const int tid = threadIdx.x;
  const float4* row = traj + (size_t)b * T_LEN;

  float sum0 = 0.f, sum1 = 0.f;
  float ph0x = 0.f, ph0z = 0.f, ph1x = 0.f, ph1z = 0.f;
  const float wstep = 2.0f * PI_F / (float)T_LEN;

  for (int t = tid; t < T_LEN; t += 256) {
    float4 r = row[t];
    sum0 += r.y;
    sum1 += r.w;
    if (t == 0)        { ph0x = r.x; ph0z = r.z; }
    if (t == T_LEN-1)  { ph1x = r.x; ph1z = r.z; }
    float w = 0.5f * (1.0f - __cosf(wstep * (float)t));
    z[t] = make_float2(r.y * w, r.w * w);
  }
  __syncthreads();

  // radix-2 DIF, 13 stages; output bit-reversed
  int ls = 12;
  for (int span = T_LEN >> 1; span >= 1; span >>= 1, --ls) {
    const float ang_scale = -PI_F / (float)span;
    for (int t = tid; t < (T_LEN >> 1); t += 256) {
      int j  = t & (span - 1);
      int i0 = ((t >> ls) << (ls + 1)) | j;
      int i1 = i0 + span;
      float2 a = z[i0];
      float2 c = z[i1];
      float2 u = make_float2(a.x + c.x, a.y + c.y);
      float2 d = make_float2(a.x - c.x, a.y - c.y);
      float sn, cs;
      __sincosf(ang_scale * (float)j, &sn, &cs);
      z[i0] = u;
      z[i1] = make_float2(d.x * cs - d.y * sn, d.x * sn + d.y * cs);
    }
    __syncthreads();
  }

  // unpack both real spectra; psd = |F|^2, bins 0..818; zero-pad to 832
  for (int k = tid; k < PSD_LDA / 2; k += 256) {
    if (k < NBINS) {
      int r1 = (int)(__brev((unsigned)k) >> 19);
      int r2 = (k == 0) ? 0 : (int)(__brev((unsigned)(T_LEN - k)) >> 19);
      float2 Zk = z[r1];
      float2 Zn = z[r2];
      float fxr = 0.5f * (Zk.x + Zn.x);
      float fxi = 0.5f * (Zk.y - Zn.y);
      float fyr = 0.5f * (Zk.y + Zn.y);
      float fyi = 0.5f * (Zn.x - Zk.x);
      psd[(size_t)b * PSD_LDA + 2*k]     = __float2bfloat16(fxr*fxr + fxi*fxi);
      psd[(size_t)b * PSD_LDA + 2*k + 1] = __float2bfloat16(fyr*fyr + fyi*fyi);
    } else {
      psd[(size_t)b * PSD_LDA + 2*k]     = __float2bfloat16(0.0f);
      psd[(size_t)b * PSD_LDA + 2*k + 1] = __float2bfloat16(0.0f);
    }
  }
  __syncthreads();

  // reductions reusing LDS
  float* zf = (float*)z;
  zf[tid]       = sum0;
  zf[256 + tid] = sum1;
  if (tid == 255) { zf[512] = ph1x; zf[513] = ph1z; }
  __syncthreads();
  if (tid == 0) {
    float s0 = 0.f, s1 = 0.f;
    for (int q = 0; q < 256; ++q) { s0 += zf[q]; s1 += zf[256 + q]; }
    vmean[b] = make_float2(s0 / (float)T_LEN, s1 / (float)T_LEN);
    const float inv2pi = 0.15915494309189535f;
    wind[b] = make_float2(fabsf(rintf((zf[512] - ph0x) * inv2pi)),
                          fabsf(rintf((zf[513] - ph0z) * inv2pi)));
  }
}

// ---------------------------------------------------------------------------
// Kernel 3: C = A * A^T, A (1024 x K bf16, stride LDA), MFMA 16x16x32 bf16.
// 64x64 tile per block; 4 waves in 2x2; each wave computes 32x32.
// global_load_lds(16B) with XOR-swizzled SOURCE colblocks; ds_read uses the
// same XOR -> <=2-way bank conflicts (rule #21: both-sides-or-neither).
// ---------------------------------------------------------------------------
template<int K, int LDA>
__global__ __launch_bounds__(256) void gram_mfma_kernel(
    const __hip_bfloat16* __restrict__ A, float* __restrict__ C) {
  __shared__ __align__(16) __hip_bfloat16 lds[2][64][64];  // 16 KB
  const int tid  = threadIdx.x;
  const int lane = tid & 63;
  const int wave = tid >> 6;
  const int wm = wave >> 1, wn = wave & 1;
  const int i0 = blockIdx.y * 64;
  const int j0 = blockIdx.x * 64;

  f32x4 acc[2][2] = {};

  for (int k0 = 0; k0 < K; k0 += 64) {
    // stage 64x64 bf16 tiles for row-block i0 (A-op) and j0 (B-op)
    #pragma unroll
    for (int r = 0; r < 2; ++r) {
      int e   = tid + 256 * r;      // 16B-block index 0..511
      int row = e >> 3;
      int cb  = e & 7;
      int scb = cb ^ (row & 7);     // involution: pre-swizzled source
      const __hip_bfloat16* srcA = A + (size_t)(i0 + row) * LDA + k0 + scb * 8;
      const __hip_bfloat16* srcB = A + (size_t)(j0 + row) * LDA + k0 + scb * 8;
      __builtin_amdgcn_global_load_lds(
          (const __attribute__((address_space(1))) void*)srcA,
          (__attribute__((address_space(3))) void*)(&lds[0][0][0] + e * 8),
          16, 0, 0);
      __builtin_amdgcn_global_load_lds(
          (const __attribute__((address_space(1))) void*)srcB,
          (__attribute__((address_space(3))) void*)(&lds[1][0][0] + e * 8),
          16, 0, 0);
    }
    __syncthreads();

    #pragma unroll
    for (int ks = 0; ks < 2; ++ks) {
      bf16x8 afr[2], bfr[2];
      #pragma unroll
      for (int m = 0; m < 2; ++m) {
        int row = wm * 32 + m * 16 + (lane & 15);
        int c   = ks * 4 + (lane >> 4);
        int cc  = c ^ (row & 7);
        afr[m] = *(const bf16x8*)(&lds[0][row][cc * 8]);
      }
      #pragma unroll
      for (int n = 0; n < 2; ++n) {
        int row = wn * 32 + n * 16 + (lane & 15);
        int c   = ks * 4 + (lane >> 4);
        int cc  = c ^ (row & 7);
        bfr[n] = *(const bf16x8*)(&lds[1][row][cc * 8]);
      }
      #pragma unroll
      for (int m = 0; m < 2; ++m)
        #pragma unroll
        for (int n = 0; n < 2; ++n)
          acc[m][n] = __builtin_amdgcn_mfma_f32_16x16x32_bf16(
              afr[m], bfr[n], acc[m][n], 0, 0, 0);
    }
    __syncthreads();
  }

  // C/D layout: col = lane&15, row = (lane>>4)*4 + reg  [m89]
  #pragma unroll
  for (int m = 0; m < 2; ++m)
    #pragma unroll
    for (int n = 0; n < 2; ++n)
      #pragma unroll
      for (int r = 0; r < 4; ++r) {
        int row = i0 + wm * 32 + m * 16 + (lane >> 4) * 4 + r;
        int col = j0 + wn * 32 + n * 16 + (lane & 15);
        C[(size_t)row * B_SZ + col] = acc[m][n][r];
      }
}

// ---------------------------------------------------------------------------
// Kernel 4: per-row loss. One block per row i.
// ---------------------------------------------------------------------------
__global__ __launch_bounds__(256) void loss_rows_kernel(
    const float* __restrict__ S,     // f fn^T raw dot (B x B)
    const float* __restrict__ G,     // psd gram (B x B); diag = n2
    const float* __restrict__ labels,    // B x 3
    const float* __restrict__ scales,    // 1
    const float2* __restrict__ vmean,
    const float2* __restrict__ wind,
    float* __restrict__ row_loss) {
  const int i = blockIdx.x;
  const int tid = threadIdx.x;
  const float inv_scale = 1.0f / scales[0];
  const float l0 = labels[i*3+0], l1 = labels[i*3+1], l2 = labels[i*3+2];
  const float2 vmi = vmean[i];
  const float2 wi  = wind[i];
  const float n2i  = G[(size_t)i * B_SZ + i];
  const float normi = sqrtf(n2i);

  float posw = 0.f, den = 0.f;
  for (int j = tid; j < B_SZ; j += 256) {
    if (j == i) continue;
    float e = __expf(S[(size_t)i * B_SZ + j] * 10.0f);  // /TEMPERATURE
    den += e;

    float d0 = (labels[j*3+0] - l0) * inv_scale;
    float d1 = (labels[j*3+1] - l1) * inv_scale;
    float d2v = (labels[j*3+2] - l2) * inv_scale;
    float pd = sqrtf(d0*d0 + d1*d1 + d2v*d2v);
    float pw = __expf(-pd * 10.0f);

    float2 vmj = vmean[j];
    float dvx = vmi.x - vmj.x, dvy = vmi.y - vmj.y;
    float v_sim = __expf(-sqrtf(dvx*dvx + dvy*dvy) * 2.0f);  // /0.5

    float n2j = G[(size_t)j * B_SZ + j];
    float g   = G[(size_t)i * B_SZ + j];
    float dd  = fmaxf(n2i + n2j - 2.0f * g, 0.0f);
    float psd_dist = sqrtf(dd);
    float norma = (i < j) ? normi : sqrtf(n2j);   // triu+transpose semantics
    float psd_sim = __expf(-psd_dist / (norma + 1e-8f));

    float2 wj = wind[j];
    float w_sim = (wi.x == wj.x && wi.y == wj.y) ? 1.0f : 0.0f;

    float kin = 0.4f * v_sim + 0.4f * psd_sim + 0.2f * w_sim;
    posw += e * pw * kin;
  }

  #pragma unroll
  for (int o = 32; o; o >>= 1) {
    posw += __shfl_down(posw, o);
    den  += __shfl_down(den, o);
  }
  __shared__ float bp[4], bd[4];
  if ((tid & 63) == 0) { bp[tid >> 6] = posw; bd[tid >> 6] = den; }
  __syncthreads();
  if (tid == 0) {
    float P = bp[0] + bp[1] + bp[2] + bp[3];
    float D = bd[0] + bd[1] + bd[2] + bd[3];
    row_loss[i] = -logf((P + 1e-8f) / (D + 1e-8f));
  }
}

// ---------------------------------------------------------------------------
// Kernel 5: mean of row losses -> scalar
// ---------------------------------------------------------------------------
__global__ __launch_bounds__(256) void reduce_mean_kernel(
    const float* __restrict__ row_loss, float* __restrict__ out) {
  int tid = threadIdx.x;
  float s = 0.f;
  for (int i = tid; i < B_SZ; i += 256) s += row_loss[i];
  #pragma unroll
  for (int o = 32; o; o >>= 1) s += __shfl_down(s, o);
  __shared__ float buf[4];
  if ((tid & 63) == 0) buf[tid >> 6] = s;
  __syncthreads();
  if (tid == 0) out[0] = (buf[0] + buf[1] + buf[2] + buf[3]) / (float)B_SZ;
}

// ---------------------------------------------------------------------------
extern "C" void kernel_launch(void* const* d_in, const int* in_sizes, int n_in,
                              void* d_out, int out_size, void* d_ws, size_t ws_size,
                              hipStream_t stream) {
  const float* features = (const float*)d_in[0];   // 1024 x 256
  const float* labels   = (const float*)d_in[1];   // 1024 x 3
  const float* traj     = (const float*)d_in[2];   // 1024 x 8192 x 4
  const float* scales   = (const float*)d_in[3];   // 1

  char* ws = (char*)d_ws;
  __hip_bfloat16* f_n = (__hip_bfloat16*)ws;                       // 1024*256 bf16
  __hip_bfloat16* psd = (__hip_bfloat16*)(ws + (size_t)B_SZ*256*2);        // 1024*1664 bf16
  float* G = (float*)(ws + (size_t)B_SZ*256*2 + (size_t)B_SZ*PSD_LDA*2);  // 1024^2 f32
  float* S = G + (size_t)B_SZ * B_SZ;                                      // 1024^2 f32
  float2* vmean = (float2*)(S + (size_t)B_SZ * B_SZ);
  float2* wind  = vmean + B_SZ;
  float* row_loss = (float*)(wind + B_SZ);

  normalize_kernel<<<B_SZ, 256, 0, stream>>>(features, f_n);
  traj_stats_kernel<<<B_SZ, 256, 0, stream>>>((const float4*)traj, psd, vmean, wind);

  dim3 grid16(16, 16);
  gram_mfma_kernel<PSD_LDA, PSD_LDA><<<grid16, 256, 0, stream>>>(psd, G);
  gram_mfma_kernel<256, 256><<<grid16, 256, 0, stream>>>(f_n, S);

  loss_rows_kernel<<<B_SZ, 256, 0, stream>>>(S, G, labels, scales, vmean, wind, row_loss);
  reduce_mean_kernel<<<1, 256, 0, stream>>>(row_loss, (float*)d_out);
}

// Round 3
// 95.841 us; speedup vs baseline: 3.2294x; 1.2217x over previous
//
#include <hip/hip_runtime.h>
#include <hip/hip_bf16.h>

#define B_SZ 1024
#define T_LEN 8192
#define NBINS 819            // T//10
#define PSD_LDA 1664         // padded bf16 row stride (zero-padded 1638..1663)
#define PI_F 3.14159265358979323846f

typedef __attribute__((ext_vector_type(8))) short bf16x8;
typedef __attribute__((ext_vector_type(4))) float f32x4;

// ---- compile-time FFT tables ----------------------------------------------
__device__ constexpr float C32T[16] = {
  1.0f, 0.980785280f, 0.923879533f, 0.831469612f, 0.707106781f, 0.555570233f,
  0.382683432f, 0.195090322f, 0.0f, -0.195090322f, -0.382683432f, -0.555570233f,
  -0.707106781f, -0.831469612f, -0.923879533f, -0.980785280f};
__device__ constexpr float S32T[16] = {   // -sin(2*pi*k/32)
  0.0f, -0.195090322f, -0.382683432f, -0.555570233f, -0.707106781f,
  -0.831469612f, -0.923879533f, -0.980785280f, -1.0f, -0.980785280f,
  -0.923879533f, -0.831469612f, -0.707106781f, -0.555570233f, -0.382683432f,
  -0.195090322f};
__device__ constexpr int BR5[32] = {   // 5-bit bit-reverse
  0,16,8,24,4,20,12,28,2,18,10,26,6,22,14,30,
  1,17,9,25,5,21,13,29,3,19,11,27,7,23,15,31};
__device__ constexpr float E8C[8] = {  // cos(pi*c/4)  (for W_8^{7c} = e^{+i pi c/4})
  1.0f, 0.707106781f, 0.0f, -0.707106781f, -1.0f, -0.707106781f, 0.0f, 0.707106781f};
__device__ constexpr float E8S[8] = {  // sin(pi*c/4)
  0.0f, 0.707106781f, 1.0f, 0.707106781f, 0.0f, -0.707106781f, -1.0f, -0.707106781f};

template<int S>
__device__ __forceinline__ void fft32_stage(float (&xr)[32], float (&xi)[32]) {
  #pragma unroll
  for (int o = 0; o < 32; o += 2 * S) {
    #pragma unroll
    for (int j = 0; j < S; ++j) {
      const int i0 = o + j, i1 = o + j + S;
      float ur = xr[i0] + xr[i1], ui = xi[i0] + xi[i1];
      float dr = xr[i0] - xr[i1], di = xi[i0] - xi[i1];
      const float c = C32T[j * (16 / S)], sn = S32T[j * (16 / S)];
      xr[i0] = ur; xi[i0] = ui;
      xr[i1] = dr * c - di * sn;
      xi[i1] = dr * sn + di * c;
    }
  }
}
__device__ __forceinline__ void fft32(float (&xr)[32], float (&xi)[32]) {
  fft32_stage<16>(xr, xi); fft32_stage<8>(xr, xi); fft32_stage<4>(xr, xi);
  fft32_stage<2>(xr, xi);  fft32_stage<1>(xr, xi);
  // output: X[k] sits at register index BR5[k]
}

// ---------------------------------------------------------------------------
// Kernel 1: normalize feature rows (B x 256) -> bf16
// ---------------------------------------------------------------------------
__global__ __launch_bounds__(256) void normalize_kernel(
    const float* __restrict__ f, __hip_bfloat16* __restrict__ fn) {
  int i = blockIdx.x;
  int t = threadIdx.x;
  float v = f[(size_t)i * 256 + t];
  float s = v * v;
  #pragma unroll
  for (int o = 32; o; o >>= 1) s += __shfl_down(s, o);
  __shared__ float buf[4];
  if ((t & 63) == 0) buf[t >> 6] = s;
  __syncthreads();
  float norm = sqrtf(buf[0] + buf[1] + buf[2] + buf[3]);
  norm = fmaxf(norm, 1e-12f);
  fn[(size_t)i * 256 + t] = __float2bfloat16(v / norm);
}

// ---------------------------------------------------------------------------
// Kernel 2: per-trajectory stats via 3-level register FFT (8192 = 32x32x8).
// Index split: n = 256a + 8b + c ; k = k0 + 32k1 + 1024k2.
// Thread tid = 8b+c holds x[256a+tid] (a=0..31) in registers.
//   S1: 32-pt FFT over a  -> *W_8192^{tid*k0}  -> LDS transpose 1
//   S2: 32-pt FFT over b  -> *W_256^{c*k1}     -> LDS transpose 2
//   S3: 8-pt over c, only k2 in {0,7} (bins 0..1023 and 7168..8191)
// ---------------------------------------------------------------------------
__global__ __launch_bounds__(256) void traj_stats_kernel(
    const float4* __restrict__ traj,
    __hip_bfloat16* __restrict__ psd,
    float2* __restrict__ vmean,
    float2* __restrict__ wind) {
  __shared__ float2 z[T_LEN];   // 64 KB

  const int tid = threadIdx.x;
  const float4* row = traj + (size_t)blockIdx.x * T_LEN;

  float xr[32], xi[32];
  float sum0 = 0.f, sum1 = 0.f;
  float ph0x = 0.f, ph0z = 0.f, ph1x = 0.f, ph1z = 0.f;
  const float wstep = 2.0f * PI_F / (float)T_LEN;

  // ---- load + window (coalesced float4; thread's a-th element = x[256a+tid])
  #pragma unroll
  for (int a = 0; a < 32; ++a) {
    int t = a * 256 + tid;
    float4 r = row[t];
    sum0 += r.y; sum1 += r.w;
    if (a == 0  && tid == 0)   { ph0x = r.x; ph0z = r.z; }
    if (a == 31 && tid == 255) { ph1x = r.x; ph1z = r.z; }
    float w = 0.5f * (1.0f - __cosf(wstep * (float)t));
    xr[a] = r.y * w;
    xi[a] = r.w * w;
  }

  // ---- stage 1: FFT over a
  fft32(xr, xi);

  // twiddle W_8192^{tid*k0}, fused with transpose-1 write (two chains for ILP)
  const int bb = tid >> 3, cc = tid & 7;
  {
    float s1, c1, s16, c16;
    __sincosf(-2.0f * PI_F * (float)tid / 8192.0f, &s1, &c1);
    __sincosf(-2.0f * PI_F * (float)tid / 512.0f,  &s16, &c16);
    float wr0 = 1.f, wi0 = 0.f, wr1 = c16, wi1 = s16;
    #pragma unroll
    for (int k0 = 0; k0 < 16; ++k0) {
      {
        const int r = BR5[k0];
        float tr = xr[r] * wr0 - xi[r] * wi0;
        float ti = xr[r] * wi0 + xi[r] * wr0;
        int slot = k0 * 256 + (bb & 24) * 8 + (((bb & 7) ^ (k0 & 7)) << 3) + ((cc ^ (bb & 7)) & 7);
        z[slot] = make_float2(tr, ti);
        float nr = wr0 * c1 - wi0 * s1; wi0 = wr0 * s1 + wi0 * c1; wr0 = nr;
      }
      {
        const int k0b = k0 + 16;
        const int r = BR5[k0b];
        float tr = xr[r] * wr1 - xi[r] * wi1;
        float ti = xr[r] * wi1 + xi[r] * wr1;
        int slot = k0b * 256 + (bb & 24) * 8 + (((bb & 7) ^ (k0b & 7)) << 3) + ((cc ^ (bb & 7)) & 7);
        z[slot] = make_float2(tr, ti);
        float nr = wr1 * c1 - wi1 * s1; wi1 = wr1 * s1 + wi1 * c1; wr1 = nr;
      }
    }
  }
  __syncthreads();

  // ---- transpose-1 read: thread (k0,c) gathers over b
  const int k0r = tid >> 3, cr = tid & 7;
  #pragma unroll
  for (int bq = 0; bq < 32; ++bq) {
    int slot = k0r * 256 + (bq & 24) * 8 + (((bq & 7) ^ (k0r & 7)) << 3) + ((cr ^ (bq & 7)) & 7);
    float2 v = z[slot];
    xr[bq] = v.x; xi[bq] = v.y;
  }
  __syncthreads();   // all reads done before in-place overwrite

  // ---- stage 2: FFT over b
  fft32(xr, xi);

  // twiddle W_256^{cr*k1}, fused with transpose-2 write
  {
    float s1, c1, s16, c16;
    __sincosf(-2.0f * PI_F * (float)cr / 256.0f, &s1, &c1);
    __sincosf(-2.0f * PI_F * (float)cr / 16.0f,  &s16, &c16);
    float wr0 = 1.f, wi0 = 0.f, wr1 = c16, wi1 = s16;
    #pragma unroll
    for (int k1 = 0; k1 < 16; ++k1) {
      {
        const int r = BR5[k1];
        float tr = xr[r] * wr0 - xi[r] * wi0;
        float ti = xr[r] * wi0 + xi[r] * wr0;
        int p = k1 * 32 + k0r;
        int slot = p * 8 + ((cr ^ ((p >> 1) & 7)) & 7);
        z[slot] = make_float2(tr, ti);
        float nr = wr0 * c1 - wi0 * s1; wi0 = wr0 * s1 + wi0 * c1; wr0 = nr;
      }
      {
        const int k1b = k1 + 16;
        const int r = BR5[k1b];
        float tr = xr[r] * wr1 - xi[r] * wi1;
        float ti = xr[r] * wi1 + xi[r] * wr1;
        int p = k1b * 32 + k0r;
        int slot = p * 8 + ((cr ^ ((p >> 1) & 7)) & 7);
        z[slot] = make_float2(tr, ti);
        float nr = wr1 * c1 - wi1 * s1; wi1 = wr1 * s1 + wi1 * c1; wr1 = nr;
      }
    }
  }
  __syncthreads();

  // ---- stage 3: 8-pt over c for 4 (k0,k1) pairs; keep k2=0 and k2=7 only
  float z0r[4], z0i[4], z7r[4], z7i[4];
  #pragma unroll
  for (int q = 0; q < 4; ++q) {
    const int p = q * 256 + tid;
    float s0r = 0.f, s0i = 0.f, s7r = 0.f, s7i = 0.f;
    #pragma unroll
    for (int c2 = 0; c2 < 8; ++c2) {
      int slot = p * 8 + ((c2 ^ ((p >> 1) & 7)) & 7);
      float2 v = z[slot];
      s0r += v.x; s0i += v.y;
      s7r += v.x * E8C[c2] - v.y * E8S[c2];
      s7i += v.x * E8S[c2] + v.y * E8C[c2];
    }
    z0r[q] = s0r; z0i[q] = s0i; z7r[q] = s7r; z7i[q] = s7i;
  }
  __syncthreads();   // all reads done
  #pragma unroll
  for (int q = 0; q < 4; ++q) {
    const int p = q * 256 + tid;
    z[p]        = make_float2(z0r[q], z0i[q]);   // Z[p],      p in [0,1024)
    z[1024 + p] = make_float2(z7r[q], z7i[q]);   // Z[7168+p]
  }
  __syncthreads();

  // ---- unpack packed real FFTs -> psd (bf16), zero-pad to PSD_LDA
  for (int k = tid; k < PSD_LDA / 2; k += 256) {
    if (k < NBINS) {
      float2 Zk = z[k];
      float2 Zn = (k == 0) ? z[0] : z[2048 - k];   // Z[8192-k] = Z7[1024-k]
      float fxr = 0.5f * (Zk.x + Zn.x);
      float fxi = 0.5f * (Zk.y - Zn.y);
      float fyr = 0.5f * (Zk.y + Zn.y);
      float fyi = 0.5f * (Zn.x - Zk.x);
      psd[(size_t)blockIdx.x * PSD_LDA + 2*k]     = __float2bfloat16(fxr*fxr + fxi*fxi);
      psd[(size_t)blockIdx.x * PSD_LDA + 2*k + 1] = __float2bfloat16(fyr*fyr + fyi*fyi);
    } else {
      psd[(size_t)blockIdx.x * PSD_LDA + 2*k]     = __float2bfloat16(0.0f);
      psd[(size_t)blockIdx.x * PSD_LDA + 2*k + 1] = __float2bfloat16(0.0f);
    }
  }
  __syncthreads();

  // ---- v_mean and winding
  float* zf = (float*)z;
  zf[tid]       = sum0;
  zf[256 + tid] = sum1;
  if (tid == 255) { zf[512] = ph1x; zf[513] = ph1z; }
  __syncthreads();
  if (tid == 0) {
    float s0 = 0.f, s1 = 0.f;
    for (int q = 0; q < 256; ++q) { s0 += zf[q]; s1 += zf[256 + q]; }
    vmean[blockIdx.x] = make_float2(s0 / (float)T_LEN, s1 / (float)T_LEN);
    const float inv2pi = 0.15915494309189535f;
    wind[blockIdx.x] = make_float2(fabsf(rintf((zf[512] - ph0x) * inv2pi)),
                                   fabsf(rintf((zf[513] - ph0z) * inv2pi)));
  }
}

// ---------------------------------------------------------------------------
// Kernel 3: C = A * A^T, A (1024 x K bf16, stride LDA), MFMA 16x16x32 bf16.
// ---------------------------------------------------------------------------
template<int K, int LDA>
__global__ __launch_bounds__(256) void gram_mfma_kernel(
    const __hip_bfloat16* __restrict__ A, float* __restrict__ C) {
  __shared__ __align__(16) __hip_bfloat16 lds[2][64][64];  // 16 KB
  const int tid  = threadIdx.x;
  const int lane = tid & 63;
  const int wave = tid >> 6;
  const int wm = wave >> 1, wn = wave & 1;
  const int i0 = blockIdx.y * 64;
  const int j0 = blockIdx.x * 64;

  f32x4 acc[2][2] = {};

  for (int k0 = 0; k0 < K; k0 += 64) {
    #pragma unroll
    for (int r = 0; r < 2; ++r) {
      int e   = tid + 256 * r;
      int row = e >> 3;
      int cb  = e & 7;
      int scb = cb ^ (row & 7);
      const __hip_bfloat16* srcA = A + (size_t)(i0 + row) * LDA + k0 + scb * 8;
      const __hip_bfloat16* srcB = A + (size_t)(j0 + row) * LDA + k0 + scb * 8;
      __builtin_amdgcn_global_load_lds(
          (const __attribute__((address_space(1))) void*)srcA,
          (__attribute__((address_space(3))) void*)(&lds[0][0][0] + e * 8),
          16, 0, 0);
      __builtin_amdgcn_global_load_lds(
          (const __attribute__((address_space(1))) void*)srcB,
          (__attribute__((address_space(3))) void*)(&lds[1][0][0] + e * 8),
          16, 0, 0);
    }
    __syncthreads();

    #pragma unroll
    for (int ks = 0; ks < 2; ++ks) {
      bf16x8 afr[2], bfr[2];
      #pragma unroll
      for (int m = 0; m < 2; ++m) {
        int row = wm * 32 + m * 16 + (lane & 15);
        int c   = ks * 4 + (lane >> 4);
        int cc  = c ^ (row & 7);
        afr[m] = *(const bf16x8*)(&lds[0][row][cc * 8]);
      }
      #pragma unroll
      for (int n = 0; n < 2; ++n) {
        int row = wn * 32 + n * 16 + (lane & 15);
        int c   = ks * 4 + (lane >> 4);
        int cc  = c ^ (row & 7);
        bfr[n] = *(const bf16x8*)(&lds[1][row][cc * 8]);
      }
      #pragma unroll
      for (int m = 0; m < 2; ++m)
        #pragma unroll
        for (int n = 0; n < 2; ++n)
          acc[m][n] = __builtin_amdgcn_mfma_f32_16x16x32_bf16(
              afr[m], bfr[n], acc[m][n], 0, 0, 0);
    }
    __syncthreads();
  }

  #pragma unroll
  for (int m = 0; m < 2; ++m)
    #pragma unroll
    for (int n = 0; n < 2; ++n)
      #pragma unroll
      for (int r = 0; r < 4; ++r) {
        int row = i0 + wm * 32 + m * 16 + (lane >> 4) * 4 + r;
        int col = j0 + wn * 32 + n * 16 + (lane & 15);
        C[(size_t)row * B_SZ + col] = acc[m][n][r];
      }
}

// ---------------------------------------------------------------------------
// Kernel 4: per-row loss. One block per row i.
// ---------------------------------------------------------------------------
__global__ __launch_bounds__(256) void loss_rows_kernel(
    const float* __restrict__ S,
    const float* __restrict__ G,
    const float* __restrict__ labels,
    const float* __restrict__ scales,
    const float2* __restrict__ vmean,
    const float2* __restrict__ wind,
    float* __restrict__ row_loss) {
  const int i = blockIdx.x;
  const int tid = threadIdx.x;
  const float inv_scale = 1.0f / scales[0];
  const float l0 = labels[i*3+0], l1 = labels[i*3+1], l2 = labels[i*3+2];
  const float2 vmi = vmean[i];
  const float2 wi  = wind[i];
  const float n2i  = G[(size_t)i * B_SZ + i];
  const float normi = sqrtf(n2i);

  float posw = 0.f, den = 0.f;
  for (int j = tid; j < B_SZ; j += 256) {
    if (j == i) continue;
    float e = __expf(S[(size_t)i * B_SZ + j] * 10.0f);
    den += e;

    float d0 = (labels[j*3+0] - l0) * inv_scale;
    float d1 = (labels[j*3+1] - l1) * inv_scale;
    float d2v = (labels[j*3+2] - l2) * inv_scale;
    float pd = sqrtf(d0*d0 + d1*d1 + d2v*d2v);
    float pw = __expf(-pd * 10.0f);

    float2 vmj = vmean[j];
    float dvx = vmi.x - vmj.x, dvy = vmi.y - vmj.y;
    float v_sim = __expf(-sqrtf(dvx*dvx + dvy*dvy) * 2.0f);

    float n2j = G[(size_t)j * B_SZ + j];
    float g   = G[(size_t)i * B_SZ + j];
    float dd  = fmaxf(n2i + n2j - 2.0f * g, 0.0f);
    float psd_dist = sqrtf(dd);
    float norma = (i < j) ? normi : sqrtf(n2j);
    float psd_sim = __expf(-psd_dist / (norma + 1e-8f));

    float2 wj = wind[j];
    float w_sim = (wi.x == wj.x && wi.y == wj.y) ? 1.0f : 0.0f;

    float kin = 0.4f * v_sim + 0.4f * psd_sim + 0.2f * w_sim;
    posw += e * pw * kin;
  }

  #pragma unroll
  for (int o = 32; o; o >>= 1) {
    posw += __shfl_down(posw, o);
    den  += __shfl_down(den, o);
  }
  __shared__ float bp[4], bd[4];
  if ((tid & 63) == 0) { bp[tid >> 6] = posw; bd[tid >> 6] = den; }
  __syncthreads();
  if (tid == 0) {
    float P = bp[0] + bp[1] + bp[2] + bp[3];
    float D = bd[0] + bd[1] + bd[2] + bd[3];
    row_loss[i] = -logf((P + 1e-8f) / (D + 1e-8f));
  }
}

// ---------------------------------------------------------------------------
// Kernel 5: mean of row losses -> scalar
// ---------------------------------------------------------------------------
__global__ __launch_bounds__(256) void reduce_mean_kernel(
    const float* __restrict__ row_loss, float* __restrict__ out) {
  int tid = threadIdx.x;
  float s = 0.f;
  for (int i = tid; i < B_SZ; i += 256) s += row_loss[i];
  #pragma unroll
  for (int o = 32; o; o >>= 1) s += __shfl_down(s, o);
  __shared__ float buf[4];
  if ((tid & 63) == 0) buf[tid >> 6] = s;
  __syncthreads();
  if (tid == 0) out[0] = (buf[0] + buf[1] + buf[2] + buf[3]) / (float)B_SZ;
}

// ---------------------------------------------------------------------------
extern "C" void kernel_launch(void* const* d_in, const int* in_sizes, int n_in,
                              void* d_out, int out_size, void* d_ws, size_t ws_size,
                              hipStream_t stream) {
  const float* features = (const float*)d_in[0];
  const float* labels   = (const float*)d_in[1];
  const float* traj     = (const float*)d_in[2];
  const float* scales   = (const float*)d_in[3];

  char* ws = (char*)d_ws;
  __hip_bfloat16* f_n = (__hip_bfloat16*)ws;
  __hip_bfloat16* psd = (__hip_bfloat16*)(ws + (size_t)B_SZ*256*2);
  float* G = (float*)(ws + (size_t)B_SZ*256*2 + (size_t)B_SZ*PSD_LDA*2);
  float* S = G + (size_t)B_SZ * B_SZ;
  float2* vmean = (float2*)(S + (size_t)B_SZ * B_SZ);
  float2* wind  = vmean + B_SZ;
  float* row_loss = (float*)(wind + B_SZ);

  normalize_kernel<<<B_SZ, 256, 0, stream>>>(features, f_n);
  traj_stats_kernel<<<B_SZ, 256, 0, stream>>>((const float4*)traj, psd, vmean, wind);

  dim3 grid16(16, 16);
  gram_mfma_kernel<PSD_LDA, PSD_LDA><<<grid16, 256, 0, stream>>>(psd, G);
  gram_mfma_kernel<256, 256><<<grid16, 256, 0, stream>>>(f_n, S);

  loss_rows_kernel<<<B_SZ, 256, 0, stream>>>(S, G, labels, scales, vmean, wind, row_loss);
  reduce_mean_kernel<<<1, 256, 0, stream>>>(row_loss, (float*)d_out);
}

// Round 4
// 81.853 us; speedup vs baseline: 3.7812x; 1.1709x over previous
//
#include <hip/hip_runtime.h>
#include <hip/hip_bf16.h>

#define B_SZ 1024
#define T_LEN 8192
#define NBINS 819            // T//10
#define PSD_LDA 1664         // padded bf16 row stride (zero-padded 1638..1663)
#define PI_F 3.14159265358979323846f

typedef __attribute__((ext_vector_type(8))) short bf16x8;
typedef __attribute__((ext_vector_type(4))) float f32x4;

// ---- compile-time FFT tables ----------------------------------------------
__device__ constexpr float C16T[8] = {
  1.0f, 0.923879533f, 0.707106781f, 0.382683432f,
  0.0f, -0.382683432f, -0.707106781f, -0.923879533f};
__device__ constexpr float S16T[8] = {   // -sin(2*pi*j/16)
  0.0f, -0.382683432f, -0.707106781f, -0.923879533f,
  -1.0f, -0.923879533f, -0.707106781f, -0.382683432f};
__device__ constexpr int BR4[16] = {0,8,4,12,2,10,6,14,1,9,5,13,3,11,7,15};
__device__ constexpr float W32C[32] = {   // cos(2*pi*m/32)
  1.0f, 0.980785280f, 0.923879533f, 0.831469612f, 0.707106781f, 0.555570233f,
  0.382683432f, 0.195090322f, 0.0f, -0.195090322f, -0.382683432f, -0.555570233f,
  -0.707106781f, -0.831469612f, -0.923879533f, -0.980785280f, -1.0f,
  -0.980785280f, -0.923879533f, -0.831469612f, -0.707106781f, -0.555570233f,
  -0.382683432f, -0.195090322f, 0.0f, 0.195090322f, 0.382683432f, 0.555570233f,
  0.707106781f, 0.831469612f, 0.923879533f, 0.980785280f};
__device__ constexpr float W32S[32] = {   // -sin(2*pi*m/32)
  0.0f, -0.195090322f, -0.382683432f, -0.555570233f, -0.707106781f,
  -0.831469612f, -0.923879533f, -0.980785280f, -1.0f, -0.980785280f,
  -0.923879533f, -0.831469612f, -0.707106781f, -0.555570233f, -0.382683432f,
  -0.195090322f, 0.0f, 0.195090322f, 0.382683432f, 0.555570233f, 0.707106781f,
  0.831469612f, 0.923879533f, 0.980785280f, 1.0f, 0.980785280f, 0.923879533f,
  0.831469612f, 0.707106781f, 0.555570233f, 0.382683432f, 0.195090322f};

template<int S>
__device__ __forceinline__ void fft16_stage(float (&xr)[16], float (&xi)[16]) {
  #pragma unroll
  for (int o = 0; o < 16; o += 2 * S) {
    #pragma unroll
    for (int j = 0; j < S; ++j) {
      const int i0 = o + j, i1 = o + j + S;
      float ur = xr[i0] + xr[i1], ui = xi[i0] + xi[i1];
      float dr = xr[i0] - xr[i1], di = xi[i0] - xi[i1];
      const float c = C16T[j * (8 / S)], sn = S16T[j * (8 / S)];
      xr[i0] = ur; xi[i0] = ui;
      xr[i1] = dr * c - di * sn;
      xi[i1] = dr * sn + di * c;
    }
  }
}
__device__ __forceinline__ void fft16(float (&xr)[16], float (&xi)[16]) {
  fft16_stage<8>(xr, xi); fft16_stage<4>(xr, xi);
  fft16_stage<2>(xr, xi); fft16_stage<1>(xr, xi);
  // X[k] sits at register index BR4[k]
}

// ---------------------------------------------------------------------------
// Kernel 1: normalize feature rows (B x 256) -> bf16
// ---------------------------------------------------------------------------
__global__ __launch_bounds__(256) void normalize_kernel(
    const float* __restrict__ f, __hip_bfloat16* __restrict__ fn) {
  int i = blockIdx.x;
  int t = threadIdx.x;
  float v = f[(size_t)i * 256 + t];
  float s = v * v;
  #pragma unroll
  for (int o = 32; o; o >>= 1) s += __shfl_down(s, o);
  __shared__ float buf[4];
  if ((t & 63) == 0) buf[t >> 6] = s;
  __syncthreads();
  float norm = sqrtf(buf[0] + buf[1] + buf[2] + buf[3]);
  norm = fmaxf(norm, 1e-12f);
  fn[(size_t)i * 256 + t] = __float2bfloat16(v / norm);
}

// ---------------------------------------------------------------------------
// Kernel 2: per-trajectory stats via register FFT, 8192 = 16 x 16 x 32.
// 512 threads, 16 complex/thread (low VGPR -> 16 waves/CU with 64KB LDS).
// n = 512a + 32b + c (tid = 32b+c); k = k0 + 16k1 + 256k2.
//   S1: FFT16 over a -> *W_8192^{tid*k0} -> T1
//   S2: FFT16 over b -> *W_512^{c*k1}    -> T2 (XOR-swizzled)
//   S3: partial DFT32 over c, k2 in {0..3} (h=0) / {28..31} (h=1)
// ---------------------------------------------------------------------------
__global__ __launch_bounds__(512, 4) void traj_stats_kernel(
    const float4* __restrict__ traj,
    __hip_bfloat16* __restrict__ psd,
    float2* __restrict__ vmean,
    float2* __restrict__ wind) {
  __shared__ float2 z[T_LEN];   // 64 KB
  __shared__ float rsum[2][8];
  __shared__ float phb[4];

  const int tid = threadIdx.x;
  const float4* row = traj + (size_t)blockIdx.x * T_LEN;

  float xr[16], xi[16];
  float sum0 = 0.f, sum1 = 0.f;
  float ph0x = 0.f, ph0z = 0.f, ph1x = 0.f, ph1z = 0.f;
  const float wstep = 2.0f * PI_F / (float)T_LEN;

  // ---- load + window, two 8-deep batches for MLP
  {
    float4 rb[8];
    #pragma unroll
    for (int i = 0; i < 8; ++i) rb[i] = row[i * 512 + tid];
    #pragma unroll
    for (int i = 0; i < 8; ++i) {
      int t = i * 512 + tid;
      sum0 += rb[i].y; sum1 += rb[i].w;
      if (i == 0 && tid == 0) { ph0x = rb[i].x; ph0z = rb[i].z; }
      float w = 0.5f * (1.0f - __cosf(wstep * (float)t));
      xr[i] = rb[i].y * w;
      xi[i] = rb[i].w * w;
    }
    #pragma unroll
    for (int i = 0; i < 8; ++i) rb[i] = row[(8 + i) * 512 + tid];
    #pragma unroll
    for (int i = 0; i < 8; ++i) {
      int t = (8 + i) * 512 + tid;
      sum0 += rb[i].y; sum1 += rb[i].w;
      if (i == 7 && tid == 511) { ph1x = rb[i].x; ph1z = rb[i].z; }
      float w = 0.5f * (1.0f - __cosf(wstep * (float)t));
      xr[8 + i] = rb[i].y * w;
      xi[8 + i] = rb[i].w * w;
    }
  }

  // ---- stage 1: FFT16 over a
  fft16(xr, xi);

  // twiddle W_8192^{tid*k0} fused with T1 write: slot = k0*512 + tid
  {
    float s1, c1, s8, c8;
    __sincosf(-2.0f * PI_F * (float)tid / 8192.0f, &s1, &c1);
    __sincosf(-2.0f * PI_F * (float)tid / 1024.0f, &s8, &c8);
    float wr0 = 1.f, wi0 = 0.f, wr1 = c8, wi1 = s8;
    #pragma unroll
    for (int k0 = 0; k0 < 8; ++k0) {
      {
        const int r = BR4[k0];
        float tr = xr[r] * wr0 - xi[r] * wi0;
        float ti = xr[r] * wi0 + xi[r] * wr0;
        z[(k0 << 9) + tid] = make_float2(tr, ti);
        float nr = wr0 * c1 - wi0 * s1; wi0 = wr0 * s1 + wi0 * c1; wr0 = nr;
      }
      {
        const int k0b = k0 + 8;
        const int r = BR4[k0b];
        float tr = xr[r] * wr1 - xi[r] * wi1;
        float ti = xr[r] * wi1 + xi[r] * wr1;
        z[(k0b << 9) + tid] = make_float2(tr, ti);
        float nr = wr1 * c1 - wi1 * s1; wi1 = wr1 * s1 + wi1 * c1; wr1 = nr;
      }
    }
  }
  __syncthreads();

  // ---- T1 read: thread (k0r, cr) gathers over b
  const int k0r = tid >> 5, cr = tid & 31;
  #pragma unroll
  for (int b = 0; b < 16; ++b) {
    float2 v = z[(k0r << 9) + (b << 5) + cr];
    xr[b] = v.x; xi[b] = v.y;
  }
  __syncthreads();

  // ---- stage 2: FFT16 over b
  fft16(xr, xi);

  // twiddle W_512^{cr*k1} fused with T2 write: slot = p*32 + (cr ^ (p&31))
  {
    float s1, c1, s8, c8;
    __sincosf(-2.0f * PI_F * (float)cr / 512.0f, &s1, &c1);
    __sincosf(-2.0f * PI_F * (float)cr / 64.0f,  &s8, &c8);
    float wr0 = 1.f, wi0 = 0.f, wr1 = c8, wi1 = s8;
    #pragma unroll
    for (int k1 = 0; k1 < 8; ++k1) {
      {
        const int r = BR4[k1];
        const int p = (k1 << 4) + k0r;
        float tr = xr[r] * wr0 - xi[r] * wi0;
        float ti = xr[r] * wi0 + xi[r] * wr0;
        z[(p << 5) + (cr ^ (p & 31))] = make_float2(tr, ti);
        float nr = wr0 * c1 - wi0 * s1; wi0 = wr0 * s1 + wi0 * c1; wr0 = nr;
      }
      {
        const int k1b = k1 + 8;
        const int r = BR4[k1b];
        const int p = (k1b << 4) + k0r;
        float tr = xr[r] * wr1 - xi[r] * wi1;
        float ti = xr[r] * wi1 + xi[r] * wr1;
        z[(p << 5) + (cr ^ (p & 31))] = make_float2(tr, ti);
        float nr = wr1 * c1 - wi1 * s1; wi1 = wr1 * s1 + wi1 * c1; wr1 = nr;
      }
    }
  }
  __syncthreads();

  // ---- stage 3: partial DFT32 over c; 2 threads per (k0,k1) pair
  const int p2 = tid & 255;
  const int h  = tid >> 8;     // wave-uniform
  float sr[4] = {0.f,0.f,0.f,0.f}, si[4] = {0.f,0.f,0.f,0.f};
  if (h == 0) {
    #pragma unroll
    for (int c2 = 0; c2 < 32; ++c2) {
      float2 v = z[(p2 << 5) + ((c2 ^ p2) & 31)];
      sr[0] += v.x; si[0] += v.y;
      #pragma unroll
      for (int j = 1; j < 4; ++j) {
        const int m = (c2 * j) & 31;
        sr[j] += v.x * W32C[m] - v.y * W32S[m];
        si[j] += v.x * W32S[m] + v.y * W32C[m];
      }
    }
  } else {
    #pragma unroll
    for (int c2 = 0; c2 < 32; ++c2) {
      float2 v = z[(p2 << 5) + ((c2 ^ p2) & 31)];
      #pragma unroll
      for (int j = 0; j < 4; ++j) {
        const int m = (c2 * (28 + j)) & 31;
        sr[j] += v.x * W32C[m] - v.y * W32S[m];
        si[j] += v.x * W32S[m] + v.y * W32C[m];
      }
    }
  }
  __syncthreads();   // all stage-3 reads done before overwrite
  // h=0: Z[p2+256j] -> z[0..1024);  h=1: Z[7168+p2+256j] -> z[1024..2048)
  #pragma unroll
  for (int j = 0; j < 4; ++j)
    z[(h << 10) + (j << 8) + p2] = make_float2(sr[j], si[j]);
  __syncthreads();

  // ---- unpack packed real FFTs -> psd (bf16), zero-pad to PSD_LDA
  for (int k = tid; k < PSD_LDA / 2; k += 512) {
    if (k < NBINS) {
      float2 Zk = z[k];
      float2 Zn = (k == 0) ? z[0] : z[2048 - k];   // Z[8192-k]
      float fxr = 0.5f * (Zk.x + Zn.x);
      float fxi = 0.5f * (Zk.y - Zn.y);
      float fyr = 0.5f * (Zk.y + Zn.y);
      float fyi = 0.5f * (Zn.x - Zk.x);
      psd[(size_t)blockIdx.x * PSD_LDA + 2*k]     = __float2bfloat16(fxr*fxr + fxi*fxi);
      psd[(size_t)blockIdx.x * PSD_LDA + 2*k + 1] = __float2bfloat16(fyr*fyr + fyi*fyi);
    } else {
      psd[(size_t)blockIdx.x * PSD_LDA + 2*k]     = __float2bfloat16(0.0f);
      psd[(size_t)blockIdx.x * PSD_LDA + 2*k + 1] = __float2bfloat16(0.0f);
    }
  }

  // ---- v_mean and winding (separate LDS arrays; no conflict with psd reads)
  #pragma unroll
  for (int o = 32; o; o >>= 1) {
    sum0 += __shfl_down(sum0, o);
    sum1 += __shfl_down(sum1, o);
  }
  if ((tid & 63) == 0) { rsum[0][tid >> 6] = sum0; rsum[1][tid >> 6] = sum1; }
  if (tid == 0)   { phb[0] = ph0x; phb[1] = ph0z; }
  if (tid == 511) { phb[2] = ph1x; phb[3] = ph1z; }
  __syncthreads();
  if (tid == 0) {
    float s0 = 0.f, s1v = 0.f;
    #pragma unroll
    for (int q = 0; q < 8; ++q) { s0 += rsum[0][q]; s1v += rsum[1][q]; }
    vmean[blockIdx.x] = make_float2(s0 / (float)T_LEN, s1v / (float)T_LEN);
    const float inv2pi = 0.15915494309189535f;
    wind[blockIdx.x] = make_float2(fabsf(rintf((phb[2] - phb[0]) * inv2pi)),
                                   fabsf(rintf((phb[3] - phb[1]) * inv2pi)));
  }
}

// ---------------------------------------------------------------------------
// Kernel 3: C = A * A^T, A (1024 x K bf16, stride LDA), MFMA 16x16x32 bf16.
// ---------------------------------------------------------------------------
template<int K, int LDA>
__global__ __launch_bounds__(256) void gram_mfma_kernel(
    const __hip_bfloat16* __restrict__ A, float* __restrict__ C) {
  __shared__ __align__(16) __hip_bfloat16 lds[2][64][64];  // 16 KB
  const int tid  = threadIdx.x;
  const int lane = tid & 63;
  const int wave = tid >> 6;
  const int wm = wave >> 1, wn = wave & 1;
  const int i0 = blockIdx.y * 64;
  const int j0 = blockIdx.x * 64;

  f32x4 acc[2][2] = {};

  for (int k0 = 0; k0 < K; k0 += 64) {
    #pragma unroll
    for (int r = 0; r < 2; ++r) {
      int e   = tid + 256 * r;
      int row = e >> 3;
      int cb  = e & 7;
      int scb = cb ^ (row & 7);
      const __hip_bfloat16* srcA = A + (size_t)(i0 + row) * LDA + k0 + scb * 8;
      const __hip_bfloat16* srcB = A + (size_t)(j0 + row) * LDA + k0 + scb * 8;
      __builtin_amdgcn_global_load_lds(
          (const __attribute__((address_space(1))) void*)srcA,
          (__attribute__((address_space(3))) void*)(&lds[0][0][0] + e * 8),
          16, 0, 0);
      __builtin_amdgcn_global_load_lds(
          (const __attribute__((address_space(1))) void*)srcB,
          (__attribute__((address_space(3))) void*)(&lds[1][0][0] + e * 8),
          16, 0, 0);
    }
    __syncthreads();

    #pragma unroll
    for (int ks = 0; ks < 2; ++ks) {
      bf16x8 afr[2], bfr[2];
      #pragma unroll
      for (int m = 0; m < 2; ++m) {
        int row = wm * 32 + m * 16 + (lane & 15);
        int c   = ks * 4 + (lane >> 4);
        int cc  = c ^ (row & 7);
        afr[m] = *(const bf16x8*)(&lds[0][row][cc * 8]);
      }
      #pragma unroll
      for (int n = 0; n < 2; ++n) {
        int row = wn * 32 + n * 16 + (lane & 15);
        int c   = ks * 4 + (lane >> 4);
        int cc  = c ^ (row & 7);
        bfr[n] = *(const bf16x8*)(&lds[1][row][cc * 8]);
      }
      #pragma unroll
      for (int m = 0; m < 2; ++m)
        #pragma unroll
        for (int n = 0; n < 2; ++n)
          acc[m][n] = __builtin_amdgcn_mfma_f32_16x16x32_bf16(
              afr[m], bfr[n], acc[m][n], 0, 0, 0);
    }
    __syncthreads();
  }

  #pragma unroll
  for (int m = 0; m < 2; ++m)
    #pragma unroll
    for (int n = 0; n < 2; ++n)
      #pragma unroll
      for (int r = 0; r < 4; ++r) {
        int row = i0 + wm * 32 + m * 16 + (lane >> 4) * 4 + r;
        int col = j0 + wn * 32 + n * 16 + (lane & 15);
        C[(size_t)row * B_SZ + col] = acc[m][n][r];
      }
}

// ---------------------------------------------------------------------------
// Kernel 4: per-row loss. One block per row i.
// ---------------------------------------------------------------------------
__global__ __launch_bounds__(256) void loss_rows_kernel(
    const float* __restrict__ S,
    const float* __restrict__ G,
    const float* __restrict__ labels,
    const float* __restrict__ scales,
    const float2* __restrict__ vmean,
    const float2* __restrict__ wind,
    float* __restrict__ row_loss) {
  const int i = blockIdx.x;
  const int tid = threadIdx.x;
  const float inv_scale = 1.0f / scales[0];
  const float l0 = labels[i*3+0], l1 = labels[i*3+1], l2 = labels[i*3+2];
  const float2 vmi = vmean[i];
  const float2 wi  = wind[i];
  const float n2i  = G[(size_t)i * B_SZ + i];
  const float normi = sqrtf(n2i);

  float posw = 0.f, den = 0.f;
  for (int j = tid; j < B_SZ; j += 256) {
    if (j == i) continue;
    float e = __expf(S[(size_t)i * B_SZ + j] * 10.0f);
    den += e;

    float d0 = (labels[j*3+0] - l0) * inv_scale;
    float d1 = (labels[j*3+1] - l1) * inv_scale;
    float d2v = (labels[j*3+2] - l2) * inv_scale;
    float pd = sqrtf(d0*d0 + d1*d1 + d2v*d2v);
    float pw = __expf(-pd * 10.0f);

    float2 vmj = vmean[j];
    float dvx = vmi.x - vmj.x, dvy = vmi.y - vmj.y;
    float v_sim = __expf(-sqrtf(dvx*dvx + dvy*dvy) * 2.0f);

    float n2j = G[(size_t)j * B_SZ + j];
    float g   = G[(size_t)i * B_SZ + j];
    float dd  = fmaxf(n2i + n2j - 2.0f * g, 0.0f);
    float psd_dist = sqrtf(dd);
    float norma = (i < j) ? normi : sqrtf(n2j);
    float psd_sim = __expf(-psd_dist / (norma + 1e-8f));

    float2 wj = wind[j];
    float w_sim = (wi.x == wj.x && wi.y == wj.y) ? 1.0f : 0.0f;

    float kin = 0.4f * v_sim + 0.4f * psd_sim + 0.2f * w_sim;
    posw += e * pw * kin;
  }

  #pragma unroll
  for (int o = 32; o; o >>= 1) {
    posw += __shfl_down(posw, o);
    den  += __shfl_down(den, o);
  }
  __shared__ float bp[4], bd[4];
  if ((tid & 63) == 0) { bp[tid >> 6] = posw; bd[tid >> 6] = den; }
  __syncthreads();
  if (tid == 0) {
    float P = bp[0] + bp[1] + bp[2] + bp[3];
    float D = bd[0] + bd[1] + bd[2] + bd[3];
    row_loss[i] = -logf((P + 1e-8f) / (D + 1e-8f));
  }
}

// ---------------------------------------------------------------------------
// Kernel 5: mean of row losses -> scalar
// ---------------------------------------------------------------------------
__global__ __launch_bounds__(256) void reduce_mean_kernel(
    const float* __restrict__ row_loss, float* __restrict__ out) {
  int tid = threadIdx.x;
  float s = 0.f;
  for (int i = tid; i < B_SZ; i += 256) s += row_loss[i];
  #pragma unroll
  for (int o = 32; o; o >>= 1) s += __shfl_down(s, o);
  __shared__ float buf[4];
  if ((tid & 63) == 0) buf[tid >> 6] = s;
  __syncthreads();
  if (tid == 0) out[0] = (buf[0] + buf[1] + buf[2] + buf[3]) / (float)B_SZ;
}

// ---------------------------------------------------------------------------
extern "C" void kernel_launch(void* const* d_in, const int* in_sizes, int n_in,
                              void* d_out, int out_size, void* d_ws, size_t ws_size,
                              hipStream_t stream) {
  const float* features = (const float*)d_in[0];
  const float* labels   = (const float*)d_in[1];
  const float* traj     = (const float*)d_in[2];
  const float* scales   = (const float*)d_in[3];

  char* ws = (char*)d_ws;
  __hip_bfloat16* f_n = (__hip_bfloat16*)ws;
  __hip_bfloat16* psd = (__hip_bfloat16*)(ws + (size_t)B_SZ*256*2);
  float* G = (float*)(ws + (size_t)B_SZ*256*2 + (size_t)B_SZ*PSD_LDA*2);
  float* S = G + (size_t)B_SZ * B_SZ;
  float2* vmean = (float2*)(S + (size_t)B_SZ * B_SZ);
  float2* wind  = vmean + B_SZ;
  float* row_loss = (float*)(wind + B_SZ);

  normalize_kernel<<<B_SZ, 256, 0, stream>>>(features, f_n);
  traj_stats_kernel<<<B_SZ, 512, 0, stream>>>((const float4*)traj, psd, vmean, wind);

  dim3 grid16(16, 16);
  gram_mfma_kernel<PSD_LDA, PSD_LDA><<<grid16, 256, 0, stream>>>(psd, G);
  gram_mfma_kernel<256, 256><<<grid16, 256, 0, stream>>>(f_n, S);

  loss_rows_kernel<<<B_SZ, 256, 0, stream>>>(S, G, labels, scales, vmean, wind, row_loss);
  reduce_mean_kernel<<<1, 256, 0, stream>>>(row_loss, (float*)d_out);
}